// Round 24
// baseline (203.947 us; speedup 1.0000x reference)
//
#include <hip/hip_runtime.h>

// 4D conv (K=3^4, SAME P=1), bf16 MFMA implicit GEMM, ONE fused kernel.
// Base = R22 champion (155.7 us): W in LDS, 2-slab __syncthreads pipeline,
// 6 waves, TPW=3, XCD-chunked tiles.
// DELTA: 2 BLOCKS/CU. ldsW holds ONE k0-group (27 taps, 27.6KB) instead of
// all 81 (82.9KB): LDS 126KB -> 70.9KB -> 2 blocks/CU, GRID 256->512.
// Model from R20/R21/R23 nulls: phase-2 time = LDS-read work + uncovered
// latency at 1.5 waves/SIMD; in-block occupancy levers failed (lockstep), so
// add an INDEPENDENT anti-phased block per CU. W re-staged per k0-group via
// the same proven global_load_lds + __syncthreads class as the slab:
// body-top sync proves all waves done with old group's af reads -> issue
// re-stage -> one drain sync -> proceed. No banned constructs (no global-af
// register dbuf [hung 3/3], no counted vmcnt).

#define D      24
#define D2_    (24*24)
#define D3_    (24*24*24)
#define D4_    (24*24*24*24)
#define CIN    16
#define COUT   32
#define TPW    3
#define NTHR   384          // 6 waves
#define GRID   512          // 2 blocks/CU (70.9KB LDS) -> all resident
#define NTILES (2*24*24)

#define ROW_USH   (2*676*8)       // 10816 ushorts = 21632 B per (b,d0,p1) row
#define WG_USH    (27*512)        // 13824 ushorts = 27648 B: one k0-group of W
#define LDS_BYTES ((WG_USH + 2*ROW_USH) * 2)   // 70912 B

#define XT_ELEMS  (2*24*26*26*26*16)
#define XT_BYTES  (XT_ELEMS*2)
#define WT_ELEMS  (81*32*16)
#define CNT_OFF_B (XT_BYTES + WT_ELEMS*2)
#define WS_NEED   (CNT_OFF_B + 64)

typedef __bf16 bf16x8 __attribute__((ext_vector_type(8)));
typedef float  f32x16 __attribute__((ext_vector_type(16)));
typedef unsigned short ushort_t;
typedef ushort_t ushort8 __attribute__((ext_vector_type(8)));
typedef ushort_t ushort4_ __attribute__((ext_vector_type(4)));

union u2b8 { ushort8 u; bf16x8 b; };

typedef const __attribute__((address_space(1))) unsigned int gu32;
typedef __attribute__((address_space(3))) unsigned int lu32;

__device__ inline ushort_t f2bf(float f) {
    union { float f; unsigned u; } x; x.f = f;
    unsigned r = x.u + 0x7FFFu + ((x.u >> 16) & 1u);   // RNE
    return (ushort_t)(r >> 16);
}

// fragment swizzle (R4-proven): spreads stride-32B b128 reads across banks
__device__ inline int fswz(int f) { return f ^ ((f >> 3) & 7); }

__global__ void __launch_bounds__(NTHR, 3) conv4d_fused(
    const float* __restrict__ x,
    const float* __restrict__ W,
    float* __restrict__ out,
    ushort_t* __restrict__ ws)
{
    extern __shared__ __align__(16) ushort_t lds[];
    ushort_t* ldsW  = lds;                       // 13824 ushorts (27648 B)
    ushort_t* slabs = lds + WG_USH;              // 2 x 10816 ushorts

    ushort_t* xt = ws;
    ushort_t* Wt = ws + XT_BYTES / 2;            // fswz'd [81][frag][8] layout
    unsigned* cnt = (unsigned*)((char*)ws + CNT_OFF_B);

    const int bk  = blockIdx.x;
    const int tid = threadIdx.x;

    // ---------------- phase 1: transpose/convert ----------------
    {
        const long gtid = (long)bk * NTHR + tid;
        const long nthr = (long)GRID * NTHR;
        for (long u = gtid; u < XT_ELEMS / 8; u += nthr) {
            const int pp = (int)(u % 676);
            long t2 = u / 676;
            const int h  = (int)(t2 & 1); t2 >>= 1;
            const int p1 = (int)(t2 % 26); t2 /= 26;
            const int d0 = (int)(t2 % 24);
            const int b  = (int)(t2 / 24);
            const int p2 = pp / 26, p3 = pp - 26 * (pp / 26);
            const int r1 = p1 - 1, r2 = p2 - 1, r3 = p3 - 1;
            ushort8 v;
            if ((unsigned)r1 < 24u && (unsigned)r2 < 24u && (unsigned)r3 < 24u) {
                const float* xp = x + (long)(b * 16 + h * 8) * D4_
                                    + d0 * D3_ + r1 * D2_ + r2 * D + r3;
                #pragma unroll
                for (int c = 0; c < 8; ++c) v[c] = f2bf(xp[(long)c * D4_]);
            } else {
                #pragma unroll
                for (int c = 0; c < 8; ++c) v[c] = 0;
            }
            *(ushort8*)&xt[u * 8] = v;
        }
        // W -> Wt with fswz layout baked in (LINEAR LDS copies later):
        // dst = tap*512 + fswz(co*2 + (ci>>3))*8 + (ci&7); tap = k0*27+k1*9+kc
        for (long i = gtid; i < WT_ELEMS; i += nthr) {
            const int tap = (int)(i >> 9);
            const int co  = (int)((i >> 4) & 31);
            const int ci  = (int)(i & 15);
            const int f   = fswz(co * 2 + (ci >> 3));
            Wt[tap * 512 + f * 8 + (ci & 7)] =
                f2bf(W[((long)co * 16 + ci) * 81 + tap]);
        }
    }

    // ---------------- grid barrier (proven structure) ----------------
    __threadfence();
    __syncthreads();
    if (tid == 0) {
        __hip_atomic_fetch_add(cnt, 1u, __ATOMIC_ACQ_REL, __HIP_MEMORY_SCOPE_AGENT);
        while (__hip_atomic_load(cnt, __ATOMIC_ACQUIRE, __HIP_MEMORY_SCOPE_AGENT)
               < (unsigned)GRID)
            __builtin_amdgcn_s_sleep(2);
    }
    __syncthreads();

    // ---------------- phase 2: implicit GEMM ----------------
    const int lane = tid & 63;
    const int wave = tid >> 6;          // 0..5
    const int col  = lane & 31;
    const int hi   = lane >> 5;

    const int afb = fswz(col * 2 + hi) * 8;   // ushort offset within tap slot

    int ppos[TPW], sbase[TPW];
    #pragma unroll
    for (int t = 0; t < TPW; ++t) {
        const int pos = (wave * TPW + t) * 32 + col;
        ppos[t]  = pos;
        sbase[t] = (hi * 676 + (pos / D) * 26 + (pos % D)) * 8;
    }

    // stage ONE k0-group of W (27 x 1KB chunks) -> ldsW. Linear, proven class.
    auto wstage = [&](int k0) {
        const ushort_t* src = Wt + (long)k0 * WG_USH;
        #pragma unroll
        for (int j = 0; j < 5; ++j) {
            const int c = wave + 6 * j;
            if (c < 27)
                __builtin_amdgcn_global_load_lds(
                    (gu32*)src + (c * 256 + lane * 4),
                    (lu32*)(ldsW + c * 512), 16, 0, 0);
        }
    };

    // XCD-chunked tile mapping: 1152 = 8 XCDs x 144 tiles; 64 blocks/XCD.
    const int xcd  = bk & 7;
    const int slot = bk >> 3;

    int wk0 = -1;   // k0 group currently in ldsW (block-uniform)

    for (int t0 = slot; t0 < 144; t0 += 64) {
        const int tile = xcd * 144 + t0;
        const int b   = tile / 576;
        const int d01 = tile % 576;
        const int d0  = d01 / 24;
        const int d1  = d01 % 24;

        const int k0lo = (d0 == 0) ? 1 : 0;
        const int k0hi = (d0 == 23) ? 1 : 2;
        const int nb   = (k0hi - k0lo + 1) * 3;   // 6 or 9 bodies

        f32x16 acc[TPW];
        #pragma unroll
        for (int t = 0; t < TPW; ++t)
            #pragma unroll
            for (int r = 0; r < 16; ++r) acc[t][r] = 0.f;

        // stage slab body i -> slabs[i&1]: 21632 B (21 x 1KB + 128B tail).
        auto stage = [&](int i) {
            const int k0 = k0lo + i / 3, k1 = i - 3 * (i / 3);
            const int r0 = d0 + k0 - 1;                 // 0..23 by construction
            const ushort_t* src = xt + ((long)(b * 24 + r0) * 26 + (d1 + k1))
                                       * (long)ROW_USH;
            ushort_t* dst = slabs + (i & 1) * ROW_USH;
            #pragma unroll
            for (int j = 0; j < 4; ++j) {
                const int c = wave + 6 * j;
                if (c < 22) {
                    const bool act = (c < 21) | (lane < 8);   // tail 128 B
                    if (act)
                        __builtin_amdgcn_global_load_lds(
                            (gu32*)src + (c * 256 + lane * 4),
                            (lu32*)(dst + c * 512), 16, 0, 0);
                }
            }
        };

        // prologue: slab(0) + (if needed) W group k0lo. Prev tile's end-sync
        // (or grid barrier) guarantees no one is still reading these buffers.
        stage(0);
        if (wk0 != k0lo) { wstage(k0lo); wk0 = k0lo; }

        for (int i = 0; i < nb; ++i) {
            __syncthreads();   // slab(i) + (if just staged) ldsW landed

            const int k0 = k0lo + i / 3, k1 = i - 3 * (i / 3);
            if (k0 != wk0) {
                // This body-top sync proved all waves finished the previous
                // group's af reads (their compute ended before the sync).
                wstage(k0); wk0 = k0;
                __syncthreads();   // drain W re-stage
            }

            if (i + 1 < nb) stage(i + 1);   // in flight for the whole body

            const ushort_t* sbuf = slabs + (i & 1) * ROW_USH;

            // af from LDS: 9 x ds_read_b128 (lgkmcnt) — no vmem dependency,
            // so nothing in this body waits on stage(i+1).
            const ushort_t* wl = ldsW + (long)(k1 * 9) * 512 + afb;
            bf16x8 af[9];
            #pragma unroll
            for (int kc = 0; kc < 9; ++kc) {
                u2b8 cvt; cvt.u = *(const ushort8*)(wl + kc * 512);
                af[kc] = cvt.b;
            }

            __builtin_amdgcn_s_setprio(1);
            #pragma unroll
            for (int kc = 0; kc < 9; ++kc) {
                const int ko = ((kc / 3) * 26 + (kc % 3)) * 8;   // imm
                #pragma unroll
                for (int t = 0; t < TPW; ++t) {
                    u2b8 cvt;
                    cvt.u = *(const ushort8*)&sbuf[sbase[t] + ko];
                    acc[t] = __builtin_amdgcn_mfma_f32_32x32x16_bf16(
                                 af[kc], cvt.b, acc[t], 0, 0, 0);
                }
            }
            __builtin_amdgcn_s_setprio(0);
        }

        // epilogue: row=co=(r&3)+8*(r>>2)+4*hi, col=pos
        float* ob = out + (long)b * COUT * D4_ + (long)d0 * D3_ + (long)d1 * D2_;
        #pragma unroll
        for (int t = 0; t < TPW; ++t) {
            #pragma unroll
            for (int r = 0; r < 16; ++r) {
                const int co = (r & 3) + 8 * (r >> 2) + 4 * hi;
                ob[(long)co * D4_ + ppos[t]] = acc[t][r];
            }
        }
        __syncthreads();   // all waves done reading slabs/ldsW before reuse
    }
}

// ===================== fallback (proven R4 kernel) =====================
__global__ __launch_bounds__(384) void conv4d_mfma_fb(
    const float* __restrict__ x,
    const float* __restrict__ W,
    float* __restrict__ out)
{
    __shared__ __align__(16) ushort_t slab[26 * 26 * CIN];
    __shared__ __align__(16) ushort_t agrp[9 * COUT * CIN];

    const int d01  = blockIdx.x;
    const int b    = blockIdx.y;
    const int d0   = d01 / D;
    const int d1   = d01 % D;
    const int tid  = threadIdx.x;
    const int lane = tid & 63;
    const int wave = tid >> 6;
    const int col  = lane & 31;
    const int hi   = lane >> 5;

    const int afbase = fswz(col * 2 + hi) * 8;
    int ppos[3], sbase[3];
    #pragma unroll
    for (int t = 0; t < 3; ++t) {
        int pos = (wave * 3 + t) * 32 + col;
        ppos[t]  = pos;
        sbase[t] = ((pos / D) * 26 + (pos % D)) * CIN + hi * 8;
    }

    f32x16 acc[3];
    #pragma unroll
    for (int t = 0; t < 3; ++t)
        #pragma unroll
        for (int r = 0; r < 16; ++r) acc[t][r] = 0.f;

    const float* xb = x + (long)b * CIN * D4_;

    for (int k0 = 0; k0 < 3; ++k0) {
        const int r0 = d0 + k0 - 1;
        if ((unsigned)r0 >= (unsigned)D) continue;
        for (int k1 = 0; k1 < 3; ++k1) {
            const int r1 = d1 + k1 - 1;
            if ((unsigned)r1 >= (unsigned)D) continue;

            __syncthreads();

            const float* xp = xb + (long)r0 * D3_ + (long)r1 * D2_;
            for (int idx = tid; idx < 26 * 26 * 2; idx += 384) {
                const int pidx = idx >> 1;
                const int h    = idx & 1;
                const int p2   = pidx / 26;
                const int p3   = pidx - p2 * 26;
                const int s2   = p2 - 1;
                const int s3   = p3 - 1;
                const bool in  = (unsigned)s2 < (unsigned)D &&
                                 (unsigned)s3 < (unsigned)D;
                const float* xs = xp + s2 * D + s3;
                ushort8 v;
                #pragma unroll
                for (int c = 0; c < 8; ++c) {
                    float f = in ? xs[(long)(h * 8 + c) * D4_] : 0.f;
                    v[c] = f2bf(f);
                }
                *(ushort8*)&slab[idx * 8] = v;
            }

            const int kw0 = k0 * 27 + k1 * 9;
            for (int u = tid; u < 9 * COUT * 4; u += 384) {
                const int tap = u >> 7;
                const int rem = u & 127;
                const int co  = rem >> 2;
                const int q   = rem & 3;
                const int ci0 = (q >> 1) * 8 + (q & 1) * 4;
                const float* wp = W + co * (CIN * 81) + kw0 + tap;
                ushort4_ v;
                #pragma unroll
                for (int c = 0; c < 4; ++c)
                    v[c] = f2bf(wp[(ci0 + c) * 81]);
                const int f  = co * 2 + (q >> 1);
                const int h2 = q & 1;
                *(ushort4_*)&agrp[tap * 512 + fswz(f) * 8 + h2 * 4] = v;
            }
            __syncthreads();

            bf16x8 af[9];
            #pragma unroll
            for (int kc = 0; kc < 9; ++kc) {
                u2b8 cvt;
                cvt.u = *(const ushort8*)&agrp[kc * 512 + afbase];
                af[kc] = cvt.b;
            }

            #pragma unroll
            for (int kc = 0; kc < 9; ++kc) {
                const int koff = ((kc / 3) * 26 + (kc % 3)) * CIN;
                #pragma unroll
                for (int t = 0; t < 3; ++t) {
                    u2b8 cvt;
                    cvt.u = *(const ushort8*)&slab[sbase[t] + koff];
                    acc[t] = __builtin_amdgcn_mfma_f32_32x32x16_bf16(
                                 af[kc], cvt.b, acc[t], 0, 0, 0);
                }
            }
        }
    }

    float* ob = out + (long)b * COUT * D4_ + (long)d0 * D3_ + (long)d1 * D2_;
    #pragma unroll
    for (int t = 0; t < 3; ++t) {
        #pragma unroll
        for (int r = 0; r < 16; ++r) {
            const int co = (r & 3) + 8 * (r >> 2) + 4 * hi;
            ob[(long)co * D4_ + ppos[t]] = acc[t][r];
        }
    }
}

extern "C" void kernel_launch(void* const* d_in, const int* in_sizes, int n_in,
                              void* d_out, int out_size, void* d_ws, size_t ws_size,
                              hipStream_t stream)
{
    const float* x = (const float*)d_in[0];
    const float* W = (const float*)d_in[1];
    float* out     = (float*)d_out;

    if (ws_size >= (size_t)WS_NEED) {
        hipFuncSetAttribute((const void*)conv4d_fused,
                            hipFuncAttributeMaxDynamicSharedMemorySize,
                            LDS_BYTES);
        hipMemsetAsync((char*)d_ws + CNT_OFF_B, 0, 64, stream);
        hipLaunchKernelGGL(conv4d_fused, dim3(GRID), dim3(NTHR), LDS_BYTES,
                           stream, x, W, out, (ushort_t*)d_ws);
    } else {
        hipLaunchKernelGGL(conv4d_mfma_fb, dim3(D * D, 2), dim3(384), 0, stream,
                           x, W, out);
    }
}

// Round 25
// 155.191 us; speedup vs baseline: 1.3142x; 1.3142x over previous
//
#include <hip/hip_runtime.h>

// 4D conv (K=3^4, SAME P=1), bf16 MFMA implicit GEMM, ONE fused kernel.
// Base = R22 champion (155.7 us): W-in-LDS (all 81 taps), 2-slab __syncthreads
// pipeline, GRID=256 (1 block/CU), XCD-chunked tiles.
// DELTA (one dial): 6 waves/TPW=3 -> 3 WAVES / TPW=6. Occupancy probes all
// REGRESSED (R17/R20/R24) => bound by per-CU LDS pipe, not latency cover.
// 3 waves halves the 6x-duplicated af reads (216->189 KB/body), narrows the
// barrier rendezvous, and doubles per-wave MFMA run length (54/body).
// acc 96 + af 36 VGPR, all statically indexed; 1 block/CU so VGPRs free.
// Banned constructs stay out (global-af cross-body dbuf hung 3/3).

#define D      24
#define D2_    (24*24)
#define D3_    (24*24*24)
#define D4_    (24*24*24*24)
#define CIN    16
#define COUT   32
#define TPW    6
#define NTHR   192          // 3 waves
#define GRID   256          // 1 block/CU (126KB LDS) -> all resident
#define NTILES (2*24*24)

#define ROW_USH   (2*676*8)       // 10816 ushorts = 21632 B per (b,d0,p1) row
#define WL_USH    (81*512)        // 41472 ushorts = 82944 B weights in LDS
#define LDS_BYTES ((WL_USH + 2*ROW_USH) * 2)   // 126208 B

#define XT_ELEMS  (2*24*26*26*26*16)
#define XT_BYTES  (XT_ELEMS*2)
#define WT_ELEMS  (81*32*16)
#define CNT_OFF_B (XT_BYTES + WT_ELEMS*2)
#define WS_NEED   (CNT_OFF_B + 64)

typedef __bf16 bf16x8 __attribute__((ext_vector_type(8)));
typedef float  f32x16 __attribute__((ext_vector_type(16)));
typedef unsigned short ushort_t;
typedef ushort_t ushort8 __attribute__((ext_vector_type(8)));
typedef ushort_t ushort4_ __attribute__((ext_vector_type(4)));

union u2b8 { ushort8 u; bf16x8 b; };

typedef const __attribute__((address_space(1))) unsigned int gu32;
typedef __attribute__((address_space(3))) unsigned int lu32;

__device__ inline ushort_t f2bf(float f) {
    union { float f; unsigned u; } x; x.f = f;
    unsigned r = x.u + 0x7FFFu + ((x.u >> 16) & 1u);   // RNE
    return (ushort_t)(r >> 16);
}

// fragment swizzle (R4-proven): spreads stride-32B b128 reads across banks
__device__ inline int fswz(int f) { return f ^ ((f >> 3) & 7); }

__global__ void __launch_bounds__(NTHR) conv4d_fused(
    const float* __restrict__ x,
    const float* __restrict__ W,
    float* __restrict__ out,
    ushort_t* __restrict__ ws)
{
    extern __shared__ __align__(16) ushort_t lds[];
    ushort_t* ldsW  = lds;                       // 41472 ushorts (82944 B)
    ushort_t* slabs = lds + WL_USH;              // 2 x 10816 ushorts

    ushort_t* xt = ws;
    ushort_t* Wt = ws + XT_BYTES / 2;            // fswz'd [81][frag][8] layout
    unsigned* cnt = (unsigned*)((char*)ws + CNT_OFF_B);

    const int bk  = blockIdx.x;
    const int tid = threadIdx.x;

    // ---------------- phase 1: transpose/convert ----------------
    {
        const long gtid = (long)bk * NTHR + tid;
        const long nthr = (long)GRID * NTHR;
        for (long u = gtid; u < XT_ELEMS / 8; u += nthr) {
            const int pp = (int)(u % 676);
            long t2 = u / 676;
            const int h  = (int)(t2 & 1); t2 >>= 1;
            const int p1 = (int)(t2 % 26); t2 /= 26;
            const int d0 = (int)(t2 % 24);
            const int b  = (int)(t2 / 24);
            const int p2 = pp / 26, p3 = pp - 26 * (pp / 26);
            const int r1 = p1 - 1, r2 = p2 - 1, r3 = p3 - 1;
            ushort8 v;
            if ((unsigned)r1 < 24u && (unsigned)r2 < 24u && (unsigned)r3 < 24u) {
                const float* xp = x + (long)(b * 16 + h * 8) * D4_
                                    + d0 * D3_ + r1 * D2_ + r2 * D + r3;
                #pragma unroll
                for (int c = 0; c < 8; ++c) v[c] = f2bf(xp[(long)c * D4_]);
            } else {
                #pragma unroll
                for (int c = 0; c < 8; ++c) v[c] = 0;
            }
            *(ushort8*)&xt[u * 8] = v;
        }
        // W -> Wt with fswz layout baked in (LINEAR LDS copy later)
        for (long i = gtid; i < WT_ELEMS; i += nthr) {
            const int tap = (int)(i >> 9);
            const int co  = (int)((i >> 4) & 31);
            const int ci  = (int)(i & 15);
            const int f   = fswz(co * 2 + (ci >> 3));
            Wt[tap * 512 + f * 8 + (ci & 7)] =
                f2bf(W[((long)co * 16 + ci) * 81 + tap]);
        }
    }

    // ---------------- grid barrier (proven structure) ----------------
    __threadfence();
    __syncthreads();
    if (tid == 0) {
        __hip_atomic_fetch_add(cnt, 1u, __ATOMIC_ACQ_REL, __HIP_MEMORY_SCOPE_AGENT);
        while (__hip_atomic_load(cnt, __ATOMIC_ACQUIRE, __HIP_MEMORY_SCOPE_AGENT)
               < (unsigned)GRID)
            __builtin_amdgcn_s_sleep(2);
    }
    __syncthreads();

    // ---------------- phase 2: implicit GEMM ----------------
    const int lane = tid & 63;
    const int wave = tid >> 6;          // 0..2
    const int col  = lane & 31;
    const int hi   = lane >> 5;

    // stage full weight block 82944 B -> ldsW (81 x 1KB chunks, 27 per wave).
    // Drained by the first tile's body-0 __syncthreads.
    for (int c = wave; c < 81; c += 3)
        __builtin_amdgcn_global_load_lds(
            (gu32*)Wt + (c * 256 + lane * 4),
            (lu32*)(ldsW + c * 512), 16, 0, 0);

    const int afb = fswz(col * 2 + hi) * 8;   // ushort offset within tap slot

    int ppos[TPW], sbase[TPW];
    #pragma unroll
    for (int t = 0; t < TPW; ++t) {
        const int pos = (wave * TPW + t) * 32 + col;   // 0..575
        ppos[t]  = pos;
        sbase[t] = (hi * 676 + (pos / D) * 26 + (pos % D)) * 8;
    }

    // XCD-chunked tile mapping: 1152 = 8 XCDs x 144 tiles; 32 blocks/XCD.
    const int xcd  = bk & 7;
    const int slot = bk >> 3;

    for (int t0 = slot; t0 < 144; t0 += 32) {
        const int tile = xcd * 144 + t0;
        const int b   = tile / 576;
        const int d01 = tile % 576;
        const int d0  = d01 / 24;
        const int d1  = d01 % 24;

        const int k0lo = (d0 == 0) ? 1 : 0;
        const int k0hi = (d0 == 23) ? 1 : 2;
        const int nb   = (k0hi - k0lo + 1) * 3;   // 6 or 9 bodies

        f32x16 acc[TPW];
        #pragma unroll
        for (int t = 0; t < TPW; ++t)
            #pragma unroll
            for (int r = 0; r < 16; ++r) acc[t][r] = 0.f;

        // stage body i -> slabs[i&1]: 21632 B (21 x 1KB + 128B tail).
        // c = wave + 3j, j=0..7; c<22; c==21 tail lanes<8.
        auto stage = [&](int i) {
            const int k0 = k0lo + i / 3, k1 = i - 3 * (i / 3);
            const int r0 = d0 + k0 - 1;                 // 0..23 by construction
            const ushort_t* src = xt + ((long)(b * 24 + r0) * 26 + (d1 + k1))
                                       * (long)ROW_USH;
            ushort_t* dst = slabs + (i & 1) * ROW_USH;
            #pragma unroll
            for (int j = 0; j < 8; ++j) {
                const int c = wave + 3 * j;
                if (c < 22) {
                    const bool act = (c < 21) | (lane < 8);   // tail 128 B
                    if (act)
                        __builtin_amdgcn_global_load_lds(
                            (gu32*)src + (c * 256 + lane * 4),
                            (lu32*)(dst + c * 512), 16, 0, 0);
                }
            }
        };

        stage(0);
        for (int i = 0; i < nb; ++i) {
            __syncthreads();   // slab(i) AND (first time) ldsW landed

            if (i + 1 < nb) stage(i + 1);   // in flight for the whole body

            const ushort_t* sbuf = slabs + (i & 1) * ROW_USH;
            const int k0 = k0lo + i / 3, k1 = i - 3 * (i / 3);

            // af from LDS: 9 x ds_read_b128 (lgkmcnt) — no vmem dependency,
            // so nothing in this body waits on stage(i+1).
            const ushort_t* wl = ldsW + (long)(k0 * 27 + k1 * 9) * 512 + afb;
            bf16x8 af[9];
            #pragma unroll
            for (int kc = 0; kc < 9; ++kc) {
                u2b8 cvt; cvt.u = *(const ushort8*)(wl + kc * 512);
                af[kc] = cvt.b;
            }

            __builtin_amdgcn_s_setprio(1);
            #pragma unroll
            for (int kc = 0; kc < 9; ++kc) {
                const int ko = ((kc / 3) * 26 + (kc % 3)) * 8;   // imm
                #pragma unroll
                for (int t = 0; t < TPW; ++t) {
                    u2b8 cvt;
                    cvt.u = *(const ushort8*)&sbuf[sbase[t] + ko];
                    acc[t] = __builtin_amdgcn_mfma_f32_32x32x16_bf16(
                                 af[kc], cvt.b, acc[t], 0, 0, 0);
                }
            }
            __builtin_amdgcn_s_setprio(0);
        }

        // epilogue: row=co=(r&3)+8*(r>>2)+4*hi, col=pos
        float* ob = out + (long)b * COUT * D4_ + (long)d0 * D3_ + (long)d1 * D2_;
        #pragma unroll
        for (int t = 0; t < TPW; ++t) {
            #pragma unroll
            for (int r = 0; r < 16; ++r) {
                const int co = (r & 3) + 8 * (r >> 2) + 4 * hi;
                ob[(long)co * D4_ + ppos[t]] = acc[t][r];
            }
        }
        __syncthreads();   // all waves done reading slab before next tile
    }
}

// ===================== fallback (proven R4 kernel) =====================
__global__ __launch_bounds__(384) void conv4d_mfma_fb(
    const float* __restrict__ x,
    const float* __restrict__ W,
    float* __restrict__ out)
{
    __shared__ __align__(16) ushort_t slab[26 * 26 * CIN];
    __shared__ __align__(16) ushort_t agrp[9 * COUT * CIN];

    const int d01  = blockIdx.x;
    const int b    = blockIdx.y;
    const int d0   = d01 / D;
    const int d1   = d01 % D;
    const int tid  = threadIdx.x;
    const int lane = tid & 63;
    const int wave = tid >> 6;
    const int col  = lane & 31;
    const int hi   = lane >> 5;

    const int afbase = fswz(col * 2 + hi) * 8;
    int ppos[3], sbase[3];
    #pragma unroll
    for (int t = 0; t < 3; ++t) {
        int pos = (wave * 3 + t) * 32 + col;
        ppos[t]  = pos;
        sbase[t] = ((pos / D) * 26 + (pos % D)) * CIN + hi * 8;
    }

    f32x16 acc[3];
    #pragma unroll
    for (int t = 0; t < 3; ++t)
        #pragma unroll
        for (int r = 0; r < 16; ++r) acc[t][r] = 0.f;

    const float* xb = x + (long)b * CIN * D4_;

    for (int k0 = 0; k0 < 3; ++k0) {
        const int r0 = d0 + k0 - 1;
        if ((unsigned)r0 >= (unsigned)D) continue;
        for (int k1 = 0; k1 < 3; ++k1) {
            const int r1 = d1 + k1 - 1;
            if ((unsigned)r1 >= (unsigned)D) continue;

            __syncthreads();

            const float* xp = xb + (long)r0 * D3_ + (long)r1 * D2_;
            for (int idx = tid; idx < 26 * 26 * 2; idx += 384) {
                const int pidx = idx >> 1;
                const int h    = idx & 1;
                const int p2   = pidx / 26;
                const int p3   = pidx - p2 * 26;
                const int s2   = p2 - 1;
                const int s3   = p3 - 1;
                const bool in  = (unsigned)s2 < (unsigned)D &&
                                 (unsigned)s3 < (unsigned)D;
                const float* xs = xp + s2 * D + s3;
                ushort8 v;
                #pragma unroll
                for (int c = 0; c < 8; ++c) {
                    float f = in ? xs[(long)(h * 8 + c) * D4_] : 0.f;
                    v[c] = f2bf(f);
                }
                *(ushort8*)&slab[idx * 8] = v;
            }

            const int kw0 = k0 * 27 + k1 * 9;
            for (int u = tid; u < 9 * COUT * 4; u += 384) {
                const int tap = u >> 7;
                const int rem = u & 127;
                const int co  = rem >> 2;
                const int q   = rem & 3;
                const int ci0 = (q >> 1) * 8 + (q & 1) * 4;
                const float* wp = W + co * (CIN * 81) + kw0 + tap;
                ushort4_ v;
                #pragma unroll
                for (int c = 0; c < 4; ++c)
                    v[c] = f2bf(wp[(ci0 + c) * 81]);
                const int f  = co * 2 + (q >> 1);
                const int h2 = q & 1;
                *(ushort4_*)&agrp[tap * 512 + fswz(f) * 8 + h2 * 4] = v;
            }
            __syncthreads();

            bf16x8 af[9];
            #pragma unroll
            for (int kc = 0; kc < 9; ++kc) {
                u2b8 cvt;
                cvt.u = *(const ushort8*)&agrp[kc * 512 + afbase];
                af[kc] = cvt.b;
            }

            #pragma unroll
            for (int kc = 0; kc < 9; ++kc) {
                const int koff = ((kc / 3) * 26 + (kc % 3)) * CIN;
                #pragma unroll
                for (int t = 0; t < 3; ++t) {
                    u2b8 cvt;
                    cvt.u = *(const ushort8*)&slab[sbase[t] + koff];
                    acc[t] = __builtin_amdgcn_mfma_f32_32x32x16_bf16(
                                 af[kc], cvt.b, acc[t], 0, 0, 0);
                }
            }
        }
    }

    float* ob = out + (long)b * COUT * D4_ + (long)d0 * D3_ + (long)d1 * D2_;
    #pragma unroll
    for (int t = 0; t < 3; ++t) {
        #pragma unroll
        for (int r = 0; r < 16; ++r) {
            const int co = (r & 3) + 8 * (r >> 2) + 4 * hi;
            ob[(long)co * D4_ + ppos[t]] = acc[t][r];
        }
    }
}

extern "C" void kernel_launch(void* const* d_in, const int* in_sizes, int n_in,
                              void* d_out, int out_size, void* d_ws, size_t ws_size,
                              hipStream_t stream)
{
    const float* x = (const float*)d_in[0];
    const float* W = (const float*)d_in[1];
    float* out     = (float*)d_out;

    if (ws_size >= (size_t)WS_NEED) {
        hipFuncSetAttribute((const void*)conv4d_fused,
                            hipFuncAttributeMaxDynamicSharedMemorySize,
                            LDS_BYTES);
        hipMemsetAsync((char*)d_ws + CNT_OFF_B, 0, 64, stream);
        hipLaunchKernelGGL(conv4d_fused, dim3(GRID), dim3(NTHR), LDS_BYTES,
                           stream, x, W, out, (ushort_t*)d_ws);
    } else {
        hipLaunchKernelGGL(conv4d_mfma_fb, dim3(D * D, 2), dim3(384), 0, stream,
                           x, W, out);
    }
}